// Round 1
// baseline (315.607 us; speedup 1.0000x reference)
//
#include <hip/hip_runtime.h>
#include <hip/hip_bf16.h>
#include <limits.h>

typedef __attribute__((ext_vector_type(8))) short short8;
typedef __attribute__((ext_vector_type(4))) float f32x4;
typedef __attribute__((ext_vector_type(4))) int i32x4;

#define B_ 8
#define T_ 512
#define NN 8000
#define NCOL 4096      // B_*T_ merged columns
#define KBINS 352      // NEST-1 == TOTAL_BINS
#define QPAD 640       // 583 padded to 5*128
#define NCHUNK 4
#define CUTQ 4

static __device__ __forceinline__ ushort bfc(float f){
  __hip_bfloat16 h = __float2bfloat16(f);
  return *reinterpret_cast<ushort*>(&h);
}

// cosg[q][n] = bf16(cos(2*pi*((q*n)%NN)/NN)) for q<HQI, else 0 (pad rows)
__global__ void gen_cos_k(ushort* __restrict__ cosg, int HQI){
  int n = blockIdx.x*256 + threadIdx.x;
  int q = blockIdx.y;
  if (n >= NN) return;
  float v = 0.f;
  if (q < HQI){
    int m = (q*n) % NN;                       // exact integer angle reduction
    v = cosf((float)m * 7.8539816339744831e-4f);  // 2*pi/8000
  }
  cosg[(size_t)q*NN + n] = bfc(v);
}

// nonzero-support scan of a band matrix row -> [lo, hi)
__global__ void bounds_k(const float* __restrict__ W, int width,
                         int* __restrict__ lo, int* __restrict__ hi){
  __shared__ int slo, shi;
  int r = blockIdx.x;
  if (threadIdx.x==0){ slo = INT_MAX; shi = -1; }
  __syncthreads();
  int mylo = INT_MAX, myhi = -1;
  for (int c = threadIdx.x; c < width; c += 256){
    if (W[(size_t)r*width + c] != 0.f){ if (c < mylo) mylo = c; if (c > myhi) myhi = c; }
  }
  atomicMin(&slo, mylo); atomicMax(&shi, myhi);
  __syncthreads();
  if (threadIdx.x==0){ lo[r] = slo; hi[r] = shi + 1; }
}

// C_partial[kc][q][col] = sum_{k in chunk} cos[q][k] * dx[col][k]
// BM=640 (all q), BN=64, BK=32, 8 waves (4M x 2N), wave tile 160x32 (10x2 frags)
__global__ __launch_bounds__(512) void gemm_k(const float* __restrict__ dx,
                                              const ushort* __restrict__ cosg,
                                              float* __restrict__ part){
  __shared__ ushort As[QPAD*32];              // 40 KB, [q][slot] with XOR swizzle
  int tid  = threadIdx.x;
  int nb   = blockIdx.x;                      // 64 col tiles
  int kc   = blockIdx.y;                      // 4 k-chunks
  int kbeg = kc*2016;
  int kend = (kbeg + 2016 < NN) ? kbeg + 2016 : NN;   // 63/63/63/61 steps
  int lane = tid & 63, widx = tid >> 6;
  int wm = widx & 3, wn = widx >> 2;
  int qw   = wm*160;
  int colw = nb*64 + wn*32;
  int lrow = lane & 15, lk = lane >> 4;
  int swz  = (lk ^ lrow) & 3;                 // q&3 == lrow&3 for our q's

  f32x4 acc[10][2];
  #pragma unroll
  for (int a=0;a<10;a++){ acc[a][0] = (f32x4)0.f; acc[a][1] = (f32x4)0.f; }

  for (int k0 = kbeg; k0 < kend; k0 += 32){
    // stage A (cos) tile: 640q x 32k bf16, reg-staged with XOR-swizzled LDS layout
    i32x4 sreg[5];
    #pragma unroll
    for (int i=0;i<5;i++){
      int u = tid + 512*i;
      int q = u >> 2, kb = u & 3;
      sreg[i] = *(const i32x4*)(cosg + (size_t)q*NN + k0 + 8*kb);
    }
    // B fragments direct from global (dx is read exactly once per element)
    short8 bfr[2];
    #pragma unroll
    for (int c=0;c<2;c++){
      const float* p = dx + (size_t)(colw + 16*c + lrow)*NN + k0 + 8*lk;
      f32x4 f0 = *(const f32x4*)p;
      f32x4 f1 = *(const f32x4*)(p+4);
      short8 s;
      s[0]=(short)bfc(f0[0]); s[1]=(short)bfc(f0[1]); s[2]=(short)bfc(f0[2]); s[3]=(short)bfc(f0[3]);
      s[4]=(short)bfc(f1[0]); s[5]=(short)bfc(f1[1]); s[6]=(short)bfc(f1[2]); s[7]=(short)bfc(f1[3]);
      bfr[c] = s;
    }
    __syncthreads();                          // previous step's frag reads done
    #pragma unroll
    for (int i=0;i<5;i++){
      int u = tid + 512*i;
      int q = u >> 2, kb = u & 3;
      *(i32x4*)(&As[q*32 + 8*((kb ^ q)&3)]) = sreg[i];
    }
    __syncthreads();                          // A tile visible
    #pragma unroll
    for (int a=0;a<10;a++){
      int q = qw + 16*a + lrow;
      short8 af = *(short8*)(&As[q*32 + 8*swz]);
      acc[a][0] = __builtin_amdgcn_mfma_f32_16x16x32_bf16(af, bfr[0], acc[a][0], 0,0,0);
      acc[a][1] = __builtin_amdgcn_mfma_f32_16x16x32_bf16(af, bfr[1], acc[a][1], 0,0,0);
    }
  }

  // D layout: col = lane&15, row = (lane>>4)*4 + r   [verified m89/m91]
  float* pb = part + (size_t)kc*QPAD*NCOL;
  #pragma unroll
  for (int a=0;a<10;a++){
    int q = qw + 16*a + 4*lk;
    #pragma unroll
    for (int c=0;c<2;c++){
      int col = colw + 16*c + lrow;
      #pragma unroll
      for (int r=0;r<4;r++) pb[(size_t)(q+r)*NCOL + col] = acc[a][c][r];
    }
  }
}

// per (b,t) column: partial-sum + nonlinear -> band matmuls -> harmonic gather
__global__ __launch_bounds__(384) void fuse_k(const float* __restrict__ dx,
        const float* __restrict__ Wf, const float* __restrict__ Wq,
        const float* __restrict__ part,
        const int* __restrict__ fLo, const int* __restrict__ fHi,
        const int* __restrict__ qLo, const int* __restrict__ qHi,
        float* __restrict__ out, int HFI, int HQI){
  __shared__ float xr[2304];
  __shared__ float yq[QPAD];
  __shared__ float tl0[KBINS];
  __shared__ float tlq[KBINS];
  int col = blockIdx.x;
  int b = col >> 9, t = col & 511;
  int tid = threadIdx.x;
  const float invs = 0.011180339887498949f;   // 1/sqrt(8000)

  for (int q = tid; q < HQI; q += 384){
    float s = 0.f;
    #pragma unroll
    for (int kc=0; kc<NCHUNK; kc++) s += part[(size_t)kc*QPAD*NCOL + (size_t)q*NCOL + col];
    s *= invs;
    float y = 0.f;
    if (q >= CUTQ && s > 0.f) y = powf(s, 0.6f);
    yq[q] = y;
  }
  for (int f = tid; f < HFI && f < 2304; f += 384) xr[f] = dx[(size_t)col*NN + f];
  __syncthreads();

  if (tid < KBINS){
    int k = tid;
    float aF = 0.f, aQ = 0.f;
    int lo = fLo[k], hx = fHi[k];
    for (int f = lo; f < hx; ++f) aF += Wf[(size_t)k*HFI + f] * xr[f];
    lo = qLo[k]; hx = qHi[k];
    for (int q = lo; q < hx; ++q) aQ += Wq[(size_t)k*HQI + q] * yq[q];
    tl0[k] = aF; tlq[k] = aQ;
  }
  __syncthreads();

  const int hids[6] = {0,48,76,96,111,124};   // argmin|CF - (k+1)*27.5|
  #pragma unroll
  for (int j=0;j<12;j++){
    int h = hids[j%6];
    for (int k = tid; k < KBINS; k += 384){
      float v;
      if (j < 6) v = (k + h < KBINS) ? tl0[k + h] : 0.f;   // har_s: shift left, pad end
      else       v = (k >= h)        ? tlq[k - h] : 0.f;   // har_c: shift right, pad front
      out[(((size_t)b*12 + j)*T_ + t)*KBINS + k] = v;
    }
  }
}

extern "C" void kernel_launch(void* const* d_in, const int* in_sizes, int n_in,
                              void* d_out, int out_size, void* d_ws, size_t ws_size,
                              hipStream_t stream){
  const float* dx = (const float*)d_in[0];
  const float* Wf = (const float*)d_in[1];
  const float* Wq = (const float*)d_in[2];
  int HFI = in_sizes[1] / KBINS;   // runtime-derived: avoids round-half-even hazard
  int HQI = in_sizes[2] / KBINS;
  float* out = (float*)d_out;
  char* ws = (char*)d_ws;

  ushort* cosg = (ushort*)ws;
  size_t off = (size_t)QPAD*NN*2;                            // 10.24 MB
  float* part = (float*)(ws + off); off += (size_t)NCHUNK*QPAD*NCOL*4;  // 41.94 MB
  int* fLo = (int*)(ws+off); off += KBINS*4;
  int* fHi = (int*)(ws+off); off += KBINS*4;
  int* qLo = (int*)(ws+off); off += KBINS*4;
  int* qHi = (int*)(ws+off); off += KBINS*4;
  (void)n_in; (void)out_size; (void)ws_size;

  gen_cos_k<<<dim3((NN+255)/256, QPAD), 256, 0, stream>>>(cosg, HQI);
  bounds_k<<<KBINS, 256, 0, stream>>>(Wf, HFI, fLo, fHi);
  bounds_k<<<KBINS, 256, 0, stream>>>(Wq, HQI, qLo, qHi);
  gemm_k<<<dim3(64, NCHUNK), 512, 0, stream>>>(dx, cosg, part);
  fuse_k<<<NCOL, 384, 0, stream>>>(dx, Wf, Wq, part, fLo, fHi, qLo, qHi, out, HFI, HQI);
}

// Round 2
// 170.846 us; speedup vs baseline: 1.8473x; 1.8473x over previous
//
#include <hip/hip_runtime.h>
#include <hip/hip_bf16.h>
#include <limits.h>

typedef __attribute__((ext_vector_type(8))) short short8;
typedef __attribute__((ext_vector_type(4))) float f32x4;

#define NN 8000
#define NCOL 4096      // 8*512 merged columns
#define KBINS 352      // NEST-1 == TOTAL_BINS
#define QPAD 640       // 583 padded
#define QH 320         // q rows per block (2 q-halves)
#define KC 4           // k chunks
#define NTILE 125      // 8000/64 k-tiles of 64
#define CUTQ 4
#define T_ 512

#define GLL16(g, l) __builtin_amdgcn_global_load_lds( \
    (const __attribute__((address_space(1))) unsigned int*)(g), \
    (__attribute__((address_space(3))) unsigned int*)(l), 16, 0, 0)

static __device__ __forceinline__ ushort bfc(float f){
  __hip_bfloat16 h = __float2bfloat16(f);
  return *reinterpret_cast<ushort*>(&h);
}

// cosg[kt][q][slot-swizzled 64]: bf16(cos(2pi*((q*n)%8000)/8000)), 0 for pad rows.
// Swizzle baked in: 8-bf16 slot s8 stored at s8 ^ (q&7)  -> conflict-free ds_read_b128.
__global__ void gen_cos_k(ushort* __restrict__ cosg, int HQI){
  int n = blockIdx.x*256 + threadIdx.x;
  int q = blockIdx.y;
  if (n >= NN) return;
  float v = 0.f;
  if (q < HQI){
    int m = (q*n) % NN;                            // exact integer angle reduction
    v = cosf((float)m * 7.8539816339744831e-4f);   // 2*pi/8000
  }
  int kt = n >> 6, s8 = (n >> 3) & 7, e = n & 7;
  cosg[(size_t)kt*(QPAD*64) + (size_t)q*64 + (((s8 ^ (q & 7)) << 3) | e)] = bfc(v);
}

// nonzero-support scan of a band matrix row -> [lo, hi)
__global__ void bounds_k(const float* __restrict__ W, int width,
                         int* __restrict__ lo, int* __restrict__ hi){
  __shared__ int slo, shi;
  int r = blockIdx.x;
  if (threadIdx.x==0){ slo = INT_MAX; shi = -1; }
  __syncthreads();
  int mylo = INT_MAX, myhi = -1;
  for (int c = threadIdx.x; c < width; c += 256){
    if (W[(size_t)r*width + c] != 0.f){ if (c < mylo) mylo = c; if (c > myhi) myhi = c; }
  }
  atomicMin(&slo, mylo); atomicMax(&shi, myhi);
  __syncthreads();
  if (threadIdx.x==0){ lo[r] = slo; hi[r] = shi + 1; }
}

// part[kc][col][q] = sum_{k in chunk} dx[col][k]*cos[q][k]
// Block: 320 q x 64 cols, BK=64, 8 waves (4 q-waves x 2 col-waves), wave tile 80q x 32col.
// A operand = dx (m=col), B operand = cos (n=q) -> D col=q (lane&15), row=col (4*lk+r).
__global__ __launch_bounds__(512) void gemm_k(const float* __restrict__ dx,
                                              const ushort* __restrict__ cosg,
                                              float* __restrict__ part){
  __shared__ ushort As[QH*64];    // cos tile, 40 KB, row stride 128B, slot-swizzled
  __shared__ ushort Bs[64*64];    // dx tile bf16, 8 KB, row stride 128B, slot-swizzled
  int tid = threadIdx.x;
  int nb = blockIdx.x, qh = blockIdx.y, kc = blockIdx.z;
  int lane = tid & 63, widx = tid >> 6;
  int wm = widx & 3, wn = widx >> 2;
  int lrow = lane & 15, lk = lane >> 4;
  int kt0 = kc*32, ktE = (kc < 3) ? kt0 + 32 : NTILE;   // 32/32/32/29 tiles

  // dx global load mapping: 8 threads per row, 8 floats each (fully coalesced)
  int drow = tid >> 3, fo = (tid & 7) * 8;
  const float* dxp = dx + (size_t)(nb*64 + drow)*NN + fo;
  // Bs write: row=drow, 16B slot (tid&7) swizzled by row
  ushort* bsp = Bs + drow*64 + (((tid & 7) ^ (drow & 7)) << 3);
  // cos staging: contiguous 40KB per tile via global_load_lds
  ushort* asp = As + tid*8;

  f32x4 acc[5][2];
  #pragma unroll
  for (int a=0;a<5;a++){ acc[a][0] = (f32x4)0.f; acc[a][1] = (f32x4)0.f; }

  f32x4 d0 = *(const f32x4*)(dxp + (size_t)kt0*64);
  f32x4 d1 = *(const f32x4*)(dxp + (size_t)kt0*64 + 4);

  for (int kt = kt0; kt < ktE; ++kt){
    short8 c8;
    c8[0]=(short)bfc(d0[0]); c8[1]=(short)bfc(d0[1]); c8[2]=(short)bfc(d0[2]); c8[3]=(short)bfc(d0[3]);
    c8[4]=(short)bfc(d1[0]); c8[5]=(short)bfc(d1[1]); c8[6]=(short)bfc(d1[2]); c8[7]=(short)bfc(d1[3]);
    if (kt + 1 < ktE){                       // prefetch next dx tile (hides under MFMA phase)
      d0 = *(const f32x4*)(dxp + (size_t)(kt+1)*64);
      d1 = *(const f32x4*)(dxp + (size_t)(kt+1)*64 + 4);
    }
    __syncthreads();                         // previous tile's frag reads done
    const ushort* cg = cosg + (size_t)kt*(QPAD*64) + (size_t)qh*(QH*64) + tid*8;
    #pragma unroll
    for (int i=0;i<5;i++) GLL16(cg + i*4096, asp + i*4096);
    *(short8*)bsp = c8;
    __syncthreads();                         // drains vmcnt+lgkmcnt: tiles visible

    #pragma unroll
    for (int p=0;p<2;p++){                   // two k=32 passes within BK=64
      short8 bfrag[5];
      #pragma unroll
      for (int a=0;a<5;a++){
        int row = wm*80 + 16*a + lrow;
        bfrag[a] = *(short8*)(As + row*64 + ((((p<<2)|lk) ^ (row & 7)) << 3));
      }
      short8 afr[2];
      #pragma unroll
      for (int c=0;c<2;c++){
        int col = wn*32 + 16*c + lrow;
        afr[c] = *(short8*)(Bs + col*64 + ((((p<<2)|lk) ^ (col & 7)) << 3));
      }
      #pragma unroll
      for (int a=0;a<5;a++){
        acc[a][0] = __builtin_amdgcn_mfma_f32_16x16x32_bf16(afr[0], bfrag[a], acc[a][0], 0,0,0);
        acc[a][1] = __builtin_amdgcn_mfma_f32_16x16x32_bf16(afr[1], bfrag[a], acc[a][1], 0,0,0);
      }
    }
  }

  // D layout: n(q) = lane&15, m(col) = 4*lk + r  -> part[kc][col][q], q contiguous
  float* pb = part + (size_t)kc*NCOL*QPAD;
  #pragma unroll
  for (int a=0;a<5;a++){
    int q = qh*QH + wm*80 + 16*a + lrow;
    #pragma unroll
    for (int c=0;c<2;c++){
      int col = nb*64 + wn*32 + 16*c + 4*lk;
      #pragma unroll
      for (int r=0;r<4;r++) pb[(size_t)(col+r)*QPAD + q] = acc[a][c][r];
    }
  }
}

// per (b,t) column: partial-sum + nonlinear -> band matmuls -> harmonic gather
__global__ __launch_bounds__(384) void fuse_k(const float* __restrict__ dx,
        const float* __restrict__ Wf, const float* __restrict__ Wq,
        const float* __restrict__ part,
        const int* __restrict__ fLo, const int* __restrict__ fHi,
        const int* __restrict__ qLo, const int* __restrict__ qHi,
        float* __restrict__ out, int HFI, int HQI){
  __shared__ float xr[2304];
  __shared__ float yq[QPAD];
  __shared__ float tl0[KBINS];
  __shared__ float tlq[KBINS];
  int col = blockIdx.x;
  int b = col >> 9, t = col & 511;
  int tid = threadIdx.x;
  const float invs = 0.011180339887498949f;   // 1/sqrt(8000)

  for (int q = tid; q < HQI; q += 384){
    float s = 0.f;
    #pragma unroll
    for (int kc=0; kc<KC; kc++) s += part[(size_t)kc*NCOL*QPAD + (size_t)col*QPAD + q];
    s *= invs;
    float y = 0.f;
    if (q >= CUTQ && s > 0.f) y = powf(s, 0.6f);
    yq[q] = y;
  }
  for (int f = tid; f < HFI && f < 2304; f += 384) xr[f] = dx[(size_t)col*NN + f];
  __syncthreads();

  if (tid < KBINS){
    int k = tid;
    float aF = 0.f, aQ = 0.f;
    int lo = fLo[k], hx = fHi[k];
    for (int f = lo; f < hx; ++f) aF += Wf[(size_t)k*HFI + f] * xr[f];
    lo = qLo[k]; hx = qHi[k];
    for (int q = lo; q < hx; ++q) aQ += Wq[(size_t)k*HQI + q] * yq[q];
    tl0[k] = aF; tlq[k] = aQ;
  }
  __syncthreads();

  const int hids[6] = {0,48,76,96,111,124};   // argmin|CF - (k+1)*27.5|
  #pragma unroll
  for (int j=0;j<12;j++){
    int h = hids[j%6];
    for (int k = tid; k < KBINS; k += 384){
      float v;
      if (j < 6) v = (k + h < KBINS) ? tl0[k + h] : 0.f;   // har_s: shift left, pad end
      else       v = (k >= h)        ? tlq[k - h] : 0.f;   // har_c: shift right, pad front
      out[(((size_t)b*12 + j)*T_ + t)*KBINS + k] = v;
    }
  }
}

extern "C" void kernel_launch(void* const* d_in, const int* in_sizes, int n_in,
                              void* d_out, int out_size, void* d_ws, size_t ws_size,
                              hipStream_t stream){
  const float* dx = (const float*)d_in[0];
  const float* Wf = (const float*)d_in[1];
  const float* Wq = (const float*)d_in[2];
  int HFI = in_sizes[1] / KBINS;   // runtime-derived (banker's-rounding safe)
  int HQI = in_sizes[2] / KBINS;
  float* out = (float*)d_out;
  char* ws = (char*)d_ws;

  ushort* cosg = (ushort*)ws;
  size_t off = (size_t)NTILE*QPAD*64*2;                       // 10.24 MB
  float* part = (float*)(ws + off); off += (size_t)KC*NCOL*QPAD*4;   // 41.94 MB
  int* fLo = (int*)(ws+off); off += KBINS*4;
  int* fHi = (int*)(ws+off); off += KBINS*4;
  int* qLo = (int*)(ws+off); off += KBINS*4;
  int* qHi = (int*)(ws+off); off += KBINS*4;
  (void)n_in; (void)out_size; (void)ws_size;

  gen_cos_k<<<dim3((NN+255)/256, QPAD), 256, 0, stream>>>(cosg, HQI);
  bounds_k<<<KBINS, 256, 0, stream>>>(Wf, HFI, fLo, fHi);
  bounds_k<<<KBINS, 256, 0, stream>>>(Wq, HQI, qLo, qHi);
  gemm_k<<<dim3(64, 2, KC), 512, 0, stream>>>(dx, cosg, part);
  fuse_k<<<NCOL, 384, 0, stream>>>(dx, Wf, Wq, part, fLo, fHi, qLo, qHi, out, HFI, HQI);
}